// Round 12
// baseline (192.257 us; speedup 1.0000x reference)
//
#include <hip/hip_runtime.h>

#define BATCH 4
#define SEQ 4096
#define IND 512
#define DH 64
#define NSPLIT 16

typedef __attribute__((ext_vector_type(8))) _Float16 f16x8;
typedef __attribute__((ext_vector_type(4))) _Float16 f16x4;
typedef __attribute__((ext_vector_type(2))) _Float16 f16x2;
typedef __attribute__((ext_vector_type(4))) float f32x4;
typedef unsigned long long u64;
typedef unsigned int u32;

#define MFMA16(a, b, c) __builtin_amdgcn_mfma_f32_16x16x32_f16(a, b, c, 0, 0, 0)

// ---- Kernel 0: transposed bit-pack, qw-major: bitsT[qw][key] bit j = mask[qw*64+j][key] ----
__global__ __launch_bounds__(256) void mask_tpack_kernel(const int* __restrict__ mask,
                                                         u64* __restrict__ bitsT) {
    int wv = blockIdx.x * 4 + (threadIdx.x >> 6);  // 0..1023
    int lane = threadIdx.x & 63;
    int qw = wv >> 4, kg = wv & 15;
    const int* mp = mask + (size_t)(qw * 64) * SEQ + kg * 256 + lane * 4;
    u64 a0 = 0, a1 = 0, a2 = 0, a3 = 0;
#pragma unroll 16
    for (int j = 0; j < 64; ++j) {
        int4 m = *(const int4*)(mp + (size_t)j * SEQ);
        a0 |= (u64)(m.x != 0) << j;
        a1 |= (u64)(m.y != 0) << j;
        a2 |= (u64)(m.z != 0) << j;
        a3 |= (u64)(m.w != 0) << j;
    }
    u64* dst = bitsT + (size_t)qw * SEQ + kg * 256 + lane * 4;
    ulonglong2 v01 = {a0, a1}, v23 = {a2, a3};
    *(ulonglong2*)(dst) = v01;
    *(ulonglong2*)(dst + 2) = v23;
}

// ---- Kernel 0b: weight prep: Wt[192][512] f16 (n-major, k-contig), bcat[192] f32 ----
// Q weights/bias pre-scaled by 0.125*log2(e): flash computes p = exp2(score).
__global__ __launch_bounds__(256) void wprep_kernel(
    const float* __restrict__ Wq, const float* __restrict__ bq,
    const float* __restrict__ Wk, const float* __restrict__ bk,
    const float* __restrict__ Wv, const float* __restrict__ bv,
    _Float16* __restrict__ Wt, float* __restrict__ bcat) {
    __shared__ float tile[64][65];
    const int bid = blockIdx.x, tid = threadIdx.x;
    const int mat = bid >> 3, k0 = (bid & 7) * 64;
    const float QS = 0.125f * 1.44269504088896f;  // 1/sqrt(64) * log2(e)
    const float* W = (mat == 0) ? Wq : ((mat == 1) ? Wk : Wv);
    const float scale = (mat == 0) ? QS : 1.0f;
    if (bid == 0 && tid < 192) {
        int m2 = tid >> 6, n = tid & 63;
        const float* bb = (m2 == 0) ? bq : ((m2 == 1) ? bk : bv);
        bcat[tid] = bb[n] * ((m2 == 0) ? QS : 1.0f);
    }
    const int n = tid & 63, r0 = tid >> 6;
#pragma unroll
    for (int i = 0; i < 16; ++i) {
        int r = r0 * 16 + i;
        tile[r][n] = W[(size_t)(k0 + r) * 64 + n];
    }
    __syncthreads();
    const int k = tid & 63, n0 = tid >> 6;
#pragma unroll
    for (int i = 0; i < 16; ++i) {
        int nn = n0 * 16 + i;
        Wt[(size_t)(mat * 64 + nn) * IND + k0 + k] = (_Float16)(tile[k][nn] * scale);
    }
}

// ---- Kernel 1: MFMA QKV projection, 3-wave blocks: wave w computes matrix w only ----
// Vt key-interleaved: s' = (s & ~31) + 2*(s&15) + ((s>>4)&1) -- matches flash's packed-P.
__global__ __launch_bounds__(192) void qkv_kernel(const float* __restrict__ X,
    const _Float16* __restrict__ Wt, const float* __restrict__ bcat,
    _Float16* __restrict__ Qh, _Float16* __restrict__ Kh, _Float16* __restrict__ Vt) {
    __shared__ __align__(16) _Float16 xs[16 * 520];  // 16 rows, stride 520 f16 (16.3 KB)
    const int tid = threadIdx.x;
    const int w = tid >> 6, lane = tid & 63, l15 = lane & 15, g = lane >> 4;
    const int m0 = blockIdx.x * 16;

    const float4* src = (const float4*)(X + (size_t)m0 * IND);
#pragma unroll
    for (int u = 0; u < 11; ++u) {
        int idx = u * 192 + tid;
        if (idx < 2048) {
            float4 x = src[idx];
            int row = idx >> 7, c4 = idx & 127;  // 128 float4 per row
            f16x4 h;
            h[0] = (_Float16)x.x; h[1] = (_Float16)x.y;
            h[2] = (_Float16)x.z; h[3] = (_Float16)x.w;
            *(f16x4*)&xs[row * 520 + c4 * 4] = h;
        }
    }
    __syncthreads();

    f32x4 acc[4];
#pragma unroll
    for (int nt = 0; nt < 4; ++nt) acc[nt] = (f32x4){0.f, 0.f, 0.f, 0.f};

    const _Float16* Wm = Wt + (size_t)(w * 64 + l15) * IND + g * 8;
#pragma unroll
    for (int kc = 0; kc < 16; ++kc) {
        f16x8 a = *(const f16x8*)&xs[l15 * 520 + kc * 32 + g * 8];
#pragma unroll
        for (int nt = 0; nt < 4; ++nt)
            acc[nt] = MFMA16(a, *(const f16x8*)(Wm + kc * 32 + (size_t)nt * 16 * IND), acc[nt]);
    }

    const int b = m0 >> 12;
    const int sbase = (m0 & (SEQ - 1)) & ~31;
    const int hi = (m0 >> 4) & 1;
#pragma unroll
    for (int nt = 0; nt < 4; ++nt) {
        float bias = bcat[w * 64 + nt * 16 + l15];
        int ncol = nt * 16 + l15;
        if (w == 0) {
#pragma unroll
            for (int r = 0; r < 4; ++r)
                Qh[(size_t)(m0 + g * 4 + r) * DH + ncol] = (_Float16)(acc[nt][r] + bias);
        } else if (w == 1) {
#pragma unroll
            for (int r = 0; r < 4; ++r)
                Kh[(size_t)(m0 + g * 4 + r) * DH + ncol] = (_Float16)(acc[nt][r] + bias);
        } else {
            _Float16* vb = Vt + ((size_t)b * DH + ncol) * SEQ + sbase + hi;
#pragma unroll
            for (int r = 0; r < 4; ++r)
                vb[2 * (g * 4 + r)] = (_Float16)(acc[nt][r] + bias);
        }
    }
}

// ---- Kernel 2: f16 MFMA flash, 64 q/wave, NSPLIT=16 -> 4096 waves (4/SIMD) ----
// Barrier-free (per-wave pbuf), gather loads from L2, f16 partial output.
__global__ __launch_bounds__(256, 4) void flash_kernel(
    const _Float16* __restrict__ Qh, const _Float16* __restrict__ Kh,
    const _Float16* __restrict__ Vt, const u64* __restrict__ bitsT,
    _Float16* __restrict__ accP, float* __restrict__ lP) {
    constexpr int KPWT = SEQ / NSPLIT;   // 256 keys per split
    constexpr int NT = KPWT / 32;        // 8 tiles
    __shared__ __align__(16) _Float16 pbuf[4][64][40];  // [wave][q][keypair], 80B row stride

    const int tid = threadIdx.x;
    const int w = tid >> 6, lane = tid & 63, l15 = lane & 15, g = lane >> 4;
    const int lin = blockIdx.x * 4 + w;               // 0..4095
    const int split = lin & (NSPLIT - 1);
    const int qt = lin >> 4;                          // 0..255
    const int b = qt >> 6;
    const int q0 = (qt & 63) * 64;                    // batch-local q base (64 rows/wave)
    const int k0base = split * KPWT;

    const _Float16* Qb = Qh + (size_t)b * SEQ * DH;
    const _Float16* Kb = Kh + (size_t)b * SEQ * DH;
    const _Float16* Vb = Vt + (size_t)b * DH * SEQ;
    const u64* bitsQ = bitsT + (size_t)(q0 >> 6) * SEQ;

    f16x8 Qa[4][2];
#pragma unroll
    for (int mi = 0; mi < 4; ++mi)
#pragma unroll
        for (int kc = 0; kc < 2; ++kc)
            Qa[mi][kc] = *(const f16x8*)(Qb + (size_t)(q0 + mi * 16 + l15) * DH + kc * 32 + g * 8);

    f32x4 O[4][4];
    float lsum[16];
#pragma unroll
    for (int mi = 0; mi < 4; ++mi)
#pragma unroll
        for (int nd = 0; nd < 4; ++nd) O[mi][nd] = (f32x4){0.f, 0.f, 0.f, 0.f};
#pragma unroll
    for (int j = 0; j < 16; ++j) lsum[j] = 0.f;

    for (int t = 0; t < NT; ++t) {
        const int k0 = k0base + t * 32;
        f16x8 Kf[2][2], Vf[4];
#pragma unroll
        for (int nt = 0; nt < 2; ++nt)
#pragma unroll
            for (int kc = 0; kc < 2; ++kc)
                Kf[nt][kc] = *(const f16x8*)(Kb + (size_t)(k0 + nt * 16 + l15) * DH + kc * 32 + g * 8);
#pragma unroll
        for (int nd = 0; nd < 4; ++nd)
            Vf[nd] = *(const f16x8*)(Vb + (size_t)(nd * 16 + l15) * SEQ + k0 + g * 8);
        u64 bw0 = bitsQ[k0 + l15];
        u64 bw1 = bitsQ[k0 + 16 + l15];

#pragma unroll
        for (int mi = 0; mi < 4; ++mi) {
            f32x4 c0 = {0.f, 0.f, 0.f, 0.f}, c1 = {0.f, 0.f, 0.f, 0.f};
            c0 = MFMA16(Qa[mi][0], Kf[0][0], c0);
            c0 = MFMA16(Qa[mi][1], Kf[0][1], c0);
            c1 = MFMA16(Qa[mi][0], Kf[1][0], c1);
            c1 = MFMA16(Qa[mi][1], Kf[1][1], c1);
            u32 ms0 = (u32)(bw0 >> (mi * 16 + (g << 2)));
            u32 ms1 = (u32)(bw1 >> (mi * 16 + (g << 2)));
#pragma unroll
            for (int r = 0; r < 4; ++r) {
                // masked -> score 0 -> p = 2^0 = 1.0 (ref: score 1e-6)
                float s0 = ((ms0 >> r) & 1u) ? c0[r] : 0.0f;
                float s1 = ((ms1 >> r) & 1u) ? c1[r] : 0.0f;
                float p0 = exp2f(s0);
                float p1 = exp2f(s1);
                lsum[mi * 4 + r] += p0 + p1;
                f16x2 pp;
                pp[0] = (_Float16)p0;
                pp[1] = (_Float16)p1;
                *(f16x2*)&pbuf[w][mi * 16 + 4 * g + r][2 * l15] = pp;  // one ds_write_b32
            }
        }
#pragma unroll
        for (int mi = 0; mi < 4; ++mi) {
            f16x8 Pa = *(const f16x8*)&pbuf[w][mi * 16 + l15][g * 8];
#pragma unroll
            for (int nd = 0; nd < 4; ++nd) O[mi][nd] = MFMA16(Pa, Vf[nd], O[mi][nd]);
        }
    }

#pragma unroll
    for (int j = 0; j < 16; ++j) {
        float v = lsum[j];
        v += __shfl_xor(v, 1);
        v += __shfl_xor(v, 2);
        v += __shfl_xor(v, 4);
        v += __shfl_xor(v, 8);
        lsum[j] = v;
    }
    _Float16* accB = accP + ((size_t)split * BATCH + b) * SEQ * DH;
    float* lB = lP + ((size_t)split * BATCH + b) * SEQ;
    if (l15 == 0) {
#pragma unroll
        for (int mi = 0; mi < 4; ++mi)
#pragma unroll
            for (int r = 0; r < 4; ++r)
                lB[q0 + mi * 16 + 4 * g + r] = lsum[mi * 4 + r];
    }
#pragma unroll
    for (int mi = 0; mi < 4; ++mi)
#pragma unroll
        for (int nd = 0; nd < 4; ++nd)
#pragma unroll
            for (int r = 0; r < 4; ++r)
                accB[(size_t)(q0 + mi * 16 + 4 * g + r) * DH + nd * 16 + l15] =
                    (_Float16)O[mi][nd][r];
}

// ---- Kernel 3: combine key-splits: out = sum(acc_f16)/sum(l) ----
__global__ __launch_bounds__(256) void reduce_kernel(const _Float16* __restrict__ accP,
                                                     const float* __restrict__ lP,
                                                     float* __restrict__ out) {
    int idx = blockIdx.x * 256 + threadIdx.x;
    int bq = idx >> 6, d = idx & 63;
    float a = 0.f, l = 0.f;
#pragma unroll
    for (int s = 0; s < NSPLIT; ++s) {
        a += (float)accP[((size_t)s * BATCH * SEQ + bq) * DH + d];
        l += lP[(size_t)s * BATCH * SEQ + bq];
    }
    out[idx] = a / l;
}

extern "C" void kernel_launch(void* const* d_in, const int* in_sizes, int n_in,
                              void* d_out, int out_size, void* d_ws, size_t ws_size,
                              hipStream_t stream) {
    const float* X = (const float*)d_in[0];
    const int* mask = (const int*)d_in[1];
    const float* Wq = (const float*)d_in[2];
    const float* bq = (const float*)d_in[3];
    const float* Wk = (const float*)d_in[4];
    const float* bk = (const float*)d_in[5];
    const float* Wv = (const float*)d_in[6];
    const float* bv = (const float*)d_in[7];
    float* out = (float*)d_out;

    char* ws = (char*)d_ws;
    _Float16* Qh = (_Float16*)ws;                       // 2 MB
    _Float16* Kh = (_Float16*)(ws + (2u << 20));        // 2 MB
    _Float16* Vt = (_Float16*)(ws + (4u << 20));        // 2 MB (key-interleaved)
    u64* bitsT = (u64*)(ws + (6u << 20));               // 2 MB
    _Float16* accP = (_Float16*)(ws + (8u << 20));      // 32 MB (16 splits, f16)
    float* lP = (float*)(ws + (40u << 20));             // 1 MB
    _Float16* Wt = (_Float16*)(ws + (41u << 20));       // 192 KB
    float* bcat = (float*)(ws + (41u << 20) + (512u << 10));  // 768 B

    wprep_kernel<<<dim3(24), dim3(256), 0, stream>>>(Wq, bq, Wk, bk, Wv, bv, Wt, bcat);
    mask_tpack_kernel<<<dim3(256), dim3(256), 0, stream>>>(mask, bitsT);
    qkv_kernel<<<dim3(BATCH * SEQ / 16), dim3(192), 0, stream>>>(X, Wt, bcat, Qh, Kh, Vt);
    flash_kernel<<<dim3(BATCH * 64 * NSPLIT / 4), dim3(256), 0, stream>>>(Qh, Kh, Vt, bitsT,
                                                                          accP, lP);
    reduce_kernel<<<dim3(BATCH * SEQ * DH / 256), dim3(256), 0, stream>>>(accP, lP, out);
}

// Round 13
// 189.670 us; speedup vs baseline: 1.0136x; 1.0136x over previous
//
#include <hip/hip_runtime.h>

#define BATCH 4
#define SEQ 4096
#define IND 512
#define DH 64
#define NSPLIT 16

typedef __attribute__((ext_vector_type(8))) _Float16 f16x8;
typedef __attribute__((ext_vector_type(4))) _Float16 f16x4;
typedef __attribute__((ext_vector_type(2))) _Float16 f16x2;
typedef __attribute__((ext_vector_type(4))) float f32x4;
typedef unsigned long long u64;
typedef unsigned int u32;

#define MFMA16(a, b, c) __builtin_amdgcn_mfma_f32_16x16x32_f16(a, b, c, 0, 0, 0)

// ---- Kernel 0: transposed bit-pack, qw-major: bitsT[qw][key] bit j = mask[qw*64+j][key] ----
__global__ __launch_bounds__(256) void mask_tpack_kernel(const int* __restrict__ mask,
                                                         u64* __restrict__ bitsT) {
    int wv = blockIdx.x * 4 + (threadIdx.x >> 6);  // 0..1023
    int lane = threadIdx.x & 63;
    int qw = wv >> 4, kg = wv & 15;
    const int* mp = mask + (size_t)(qw * 64) * SEQ + kg * 256 + lane * 4;
    u64 a0 = 0, a1 = 0, a2 = 0, a3 = 0;
#pragma unroll 16
    for (int j = 0; j < 64; ++j) {
        int4 m = *(const int4*)(mp + (size_t)j * SEQ);
        a0 |= (u64)(m.x != 0) << j;
        a1 |= (u64)(m.y != 0) << j;
        a2 |= (u64)(m.z != 0) << j;
        a3 |= (u64)(m.w != 0) << j;
    }
    u64* dst = bitsT + (size_t)qw * SEQ + kg * 256 + lane * 4;
    ulonglong2 v01 = {a0, a1}, v23 = {a2, a3};
    *(ulonglong2*)(dst) = v01;
    *(ulonglong2*)(dst + 2) = v23;
}

// ---- Kernel 0b: weight prep: Wt[192][512] f16 (n-major, k-contig), bcat[192] f32 ----
// Q weights/bias pre-scaled by 0.125*log2(e): flash computes p = exp2(score).
__global__ __launch_bounds__(256) void wprep_kernel(
    const float* __restrict__ Wq, const float* __restrict__ bq,
    const float* __restrict__ Wk, const float* __restrict__ bk,
    const float* __restrict__ Wv, const float* __restrict__ bv,
    _Float16* __restrict__ Wt, float* __restrict__ bcat) {
    __shared__ float tile[64][65];
    const int bid = blockIdx.x, tid = threadIdx.x;
    const int mat = bid >> 3, k0 = (bid & 7) * 64;
    const float QS = 0.125f * 1.44269504088896f;  // 1/sqrt(64) * log2(e)
    const float* W = (mat == 0) ? Wq : ((mat == 1) ? Wk : Wv);
    const float scale = (mat == 0) ? QS : 1.0f;
    if (bid == 0 && tid < 192) {
        int m2 = tid >> 6, n = tid & 63;
        const float* bb = (m2 == 0) ? bq : ((m2 == 1) ? bk : bv);
        bcat[tid] = bb[n] * ((m2 == 0) ? QS : 1.0f);
    }
    const int n = tid & 63, r0 = tid >> 6;
#pragma unroll
    for (int i = 0; i < 16; ++i) {
        int r = r0 * 16 + i;
        tile[r][n] = W[(size_t)(k0 + r) * 64 + n];
    }
    __syncthreads();
    const int k = tid & 63, n0 = tid >> 6;
#pragma unroll
    for (int i = 0; i < 16; ++i) {
        int nn = n0 * 16 + i;
        Wt[(size_t)(mat * 64 + nn) * IND + k0 + k] = (_Float16)(tile[k][nn] * scale);
    }
}

// ---- Kernel 1: MFMA QKV projection, 3-wave blocks: wave w computes matrix w only ----
// Vt key-interleaved: s' = (s & ~31) + 2*(s&15) + ((s>>4)&1) -- matches flash's packed-P.
__global__ __launch_bounds__(192) void qkv_kernel(const float* __restrict__ X,
    const _Float16* __restrict__ Wt, const float* __restrict__ bcat,
    _Float16* __restrict__ Qh, _Float16* __restrict__ Kh, _Float16* __restrict__ Vt) {
    __shared__ __align__(16) _Float16 xs[16 * 520];  // 16 rows, stride 520 f16 (16.3 KB)
    const int tid = threadIdx.x;
    const int w = tid >> 6, lane = tid & 63, l15 = lane & 15, g = lane >> 4;
    const int m0 = blockIdx.x * 16;

    const float4* src = (const float4*)(X + (size_t)m0 * IND);
#pragma unroll
    for (int u = 0; u < 11; ++u) {
        int idx = u * 192 + tid;
        if (idx < 2048) {
            float4 x = src[idx];
            int row = idx >> 7, c4 = idx & 127;  // 128 float4 per row
            f16x4 h;
            h[0] = (_Float16)x.x; h[1] = (_Float16)x.y;
            h[2] = (_Float16)x.z; h[3] = (_Float16)x.w;
            *(f16x4*)&xs[row * 520 + c4 * 4] = h;
        }
    }
    __syncthreads();

    f32x4 acc[4];
#pragma unroll
    for (int nt = 0; nt < 4; ++nt) acc[nt] = (f32x4){0.f, 0.f, 0.f, 0.f};

    const _Float16* Wm = Wt + (size_t)(w * 64 + l15) * IND + g * 8;
#pragma unroll
    for (int kc = 0; kc < 16; ++kc) {
        f16x8 a = *(const f16x8*)&xs[l15 * 520 + kc * 32 + g * 8];
#pragma unroll
        for (int nt = 0; nt < 4; ++nt)
            acc[nt] = MFMA16(a, *(const f16x8*)(Wm + kc * 32 + (size_t)nt * 16 * IND), acc[nt]);
    }

    const int b = m0 >> 12;
    const int sbase = (m0 & (SEQ - 1)) & ~31;
    const int hi = (m0 >> 4) & 1;
#pragma unroll
    for (int nt = 0; nt < 4; ++nt) {
        float bias = bcat[w * 64 + nt * 16 + l15];
        int ncol = nt * 16 + l15;
        if (w == 0) {
#pragma unroll
            for (int r = 0; r < 4; ++r)
                Qh[(size_t)(m0 + g * 4 + r) * DH + ncol] = (_Float16)(acc[nt][r] + bias);
        } else if (w == 1) {
#pragma unroll
            for (int r = 0; r < 4; ++r)
                Kh[(size_t)(m0 + g * 4 + r) * DH + ncol] = (_Float16)(acc[nt][r] + bias);
        } else {
            _Float16* vb = Vt + ((size_t)b * DH + ncol) * SEQ + sbase + hi;
#pragma unroll
            for (int r = 0; r < 4; ++r)
                vb[2 * (g * 4 + r)] = (_Float16)(acc[nt][r] + bias);
        }
    }
}

// ---- Kernel 2: f16 MFMA flash, 64 q/wave, NSPLIT=16, XCD-pinned mapping ----
// 1024 blocks = 4/CU = 4 waves/SIMD; per-XCD working set (K,V half + Q + bits) ~2MB < L2.
__global__ __launch_bounds__(256, 4) void flash_kernel(
    const _Float16* __restrict__ Qh, const _Float16* __restrict__ Kh,
    const _Float16* __restrict__ Vt, const u64* __restrict__ bitsT,
    _Float16* __restrict__ accP, float* __restrict__ lP) {
    constexpr int KPWT = SEQ / NSPLIT;   // 256 keys per split
    constexpr int NT = KPWT / 32;        // 8 tiles
    __shared__ __align__(16) _Float16 pbuf[4][64][40];  // [wave][q][keypair], 80B row stride

    const int tid = threadIdx.x;
    const int w = tid >> 6, lane = tid & 63, l15 = lane & 15, g = lane >> 4;
    const int bid = blockIdx.x;                      // 1024 blocks
    const int xcd = bid & 7, i = bid >> 3;           // i: 0..127
    const int b = xcd >> 1;                          // batch pinned to XCD pair
    const int split = (xcd & 1) * 8 + (i & 7);       // 8 splits per XCD
    const int qblk = i >> 3;                         // 0..15
    const int q0 = qblk * 256 + w * 64;              // batch-local q base (64 rows/wave)
    const int k0base = split * KPWT;

    const _Float16* Qb = Qh + (size_t)b * SEQ * DH;
    const _Float16* Kb = Kh + (size_t)b * SEQ * DH;
    const _Float16* Vb = Vt + (size_t)b * DH * SEQ;
    const u64* bitsQ = bitsT + (size_t)(q0 >> 6) * SEQ;

    f16x8 Qa[4][2];
#pragma unroll
    for (int mi = 0; mi < 4; ++mi)
#pragma unroll
        for (int kc = 0; kc < 2; ++kc)
            Qa[mi][kc] = *(const f16x8*)(Qb + (size_t)(q0 + mi * 16 + l15) * DH + kc * 32 + g * 8);

    f32x4 O[4][4];
    float lsum[16];
#pragma unroll
    for (int mi = 0; mi < 4; ++mi)
#pragma unroll
        for (int nd = 0; nd < 4; ++nd) O[mi][nd] = (f32x4){0.f, 0.f, 0.f, 0.f};
#pragma unroll
    for (int j = 0; j < 16; ++j) lsum[j] = 0.f;

    for (int t = 0; t < NT; ++t) {
        const int k0 = k0base + t * 32;
        f16x8 Kf[2][2], Vf[4];
#pragma unroll
        for (int nt = 0; nt < 2; ++nt)
#pragma unroll
            for (int kc = 0; kc < 2; ++kc)
                Kf[nt][kc] = *(const f16x8*)(Kb + (size_t)(k0 + nt * 16 + l15) * DH + kc * 32 + g * 8);
#pragma unroll
        for (int nd = 0; nd < 4; ++nd)
            Vf[nd] = *(const f16x8*)(Vb + (size_t)(nd * 16 + l15) * SEQ + k0 + g * 8);
        u64 bw0 = bitsQ[k0 + l15];
        u64 bw1 = bitsQ[k0 + 16 + l15];

#pragma unroll
        for (int mi = 0; mi < 4; ++mi) {
            f32x4 c0 = {0.f, 0.f, 0.f, 0.f}, c1 = {0.f, 0.f, 0.f, 0.f};
            c0 = MFMA16(Qa[mi][0], Kf[0][0], c0);
            c0 = MFMA16(Qa[mi][1], Kf[0][1], c0);
            c1 = MFMA16(Qa[mi][0], Kf[1][0], c1);
            c1 = MFMA16(Qa[mi][1], Kf[1][1], c1);
            u32 ms0 = (u32)(bw0 >> (mi * 16 + (g << 2)));
            u32 ms1 = (u32)(bw1 >> (mi * 16 + (g << 2)));
#pragma unroll
            for (int r = 0; r < 4; ++r) {
                // masked -> score 0 -> p = 2^0 = 1.0 (ref: score 1e-6)
                float s0 = ((ms0 >> r) & 1u) ? c0[r] : 0.0f;
                float s1 = ((ms1 >> r) & 1u) ? c1[r] : 0.0f;
                float p0 = exp2f(s0);
                float p1 = exp2f(s1);
                lsum[mi * 4 + r] += p0 + p1;
                f16x2 pp;
                pp[0] = (_Float16)p0;
                pp[1] = (_Float16)p1;
                *(f16x2*)&pbuf[w][mi * 16 + 4 * g + r][2 * l15] = pp;  // one ds_write_b32
            }
        }
#pragma unroll
        for (int mi = 0; mi < 4; ++mi) {
            f16x8 Pa = *(const f16x8*)&pbuf[w][mi * 16 + l15][g * 8];
#pragma unroll
            for (int nd = 0; nd < 4; ++nd) O[mi][nd] = MFMA16(Pa, Vf[nd], O[mi][nd]);
        }
    }

#pragma unroll
    for (int j = 0; j < 16; ++j) {
        float v = lsum[j];
        v += __shfl_xor(v, 1);
        v += __shfl_xor(v, 2);
        v += __shfl_xor(v, 4);
        v += __shfl_xor(v, 8);
        lsum[j] = v;
    }
    _Float16* accB = accP + ((size_t)split * BATCH + b) * SEQ * DH;
    float* lB = lP + ((size_t)split * BATCH + b) * SEQ;
    if (l15 == 0) {
#pragma unroll
        for (int mi = 0; mi < 4; ++mi)
#pragma unroll
            for (int r = 0; r < 4; ++r)
                lB[q0 + mi * 16 + 4 * g + r] = lsum[mi * 4 + r];
    }
#pragma unroll
    for (int mi = 0; mi < 4; ++mi)
#pragma unroll
        for (int nd = 0; nd < 4; ++nd)
#pragma unroll
            for (int r = 0; r < 4; ++r)
                accB[(size_t)(q0 + mi * 16 + 4 * g + r) * DH + nd * 16 + l15] =
                    (_Float16)O[mi][nd][r];
}

// ---- Kernel 3: combine key-splits: out = sum(acc_f16)/sum(l) ----
__global__ __launch_bounds__(256) void reduce_kernel(const _Float16* __restrict__ accP,
                                                     const float* __restrict__ lP,
                                                     float* __restrict__ out) {
    int idx = blockIdx.x * 256 + threadIdx.x;
    int bq = idx >> 6, d = idx & 63;
    float a = 0.f, l = 0.f;
#pragma unroll
    for (int s = 0; s < NSPLIT; ++s) {
        a += (float)accP[((size_t)s * BATCH * SEQ + bq) * DH + d];
        l += lP[(size_t)s * BATCH * SEQ + bq];
    }
    out[idx] = a / l;
}

extern "C" void kernel_launch(void* const* d_in, const int* in_sizes, int n_in,
                              void* d_out, int out_size, void* d_ws, size_t ws_size,
                              hipStream_t stream) {
    const float* X = (const float*)d_in[0];
    const int* mask = (const int*)d_in[1];
    const float* Wq = (const float*)d_in[2];
    const float* bq = (const float*)d_in[3];
    const float* Wk = (const float*)d_in[4];
    const float* bk = (const float*)d_in[5];
    const float* Wv = (const float*)d_in[6];
    const float* bv = (const float*)d_in[7];
    float* out = (float*)d_out;

    char* ws = (char*)d_ws;
    _Float16* Qh = (_Float16*)ws;                       // 2 MB
    _Float16* Kh = (_Float16*)(ws + (2u << 20));        // 2 MB
    _Float16* Vt = (_Float16*)(ws + (4u << 20));        // 2 MB (key-interleaved)
    u64* bitsT = (u64*)(ws + (6u << 20));               // 2 MB
    _Float16* accP = (_Float16*)(ws + (8u << 20));      // 32 MB (16 splits, f16)
    float* lP = (float*)(ws + (40u << 20));             // 1 MB
    _Float16* Wt = (_Float16*)(ws + (41u << 20));       // 192 KB
    float* bcat = (float*)(ws + (41u << 20) + (512u << 10));  // 768 B

    wprep_kernel<<<dim3(24), dim3(256), 0, stream>>>(Wq, bq, Wk, bk, Wv, bv, Wt, bcat);
    mask_tpack_kernel<<<dim3(256), dim3(256), 0, stream>>>(mask, bitsT);
    qkv_kernel<<<dim3(BATCH * SEQ / 16), dim3(192), 0, stream>>>(X, Wt, bcat, Qh, Kh, Vt);
    flash_kernel<<<dim3(1024), dim3(256), 0, stream>>>(Qh, Kh, Vt, bitsT, accP, lP);
    reduce_kernel<<<dim3(BATCH * SEQ * DH / 256), dim3(256), 0, stream>>>(accP, lP, out);
}

// Round 14
// 107.615 us; speedup vs baseline: 1.7865x; 1.7625x over previous
//
#include <hip/hip_runtime.h>

#define BATCH 4
#define SEQ 4096
#define IND 512
#define DH 64
#define NSPLIT 8

typedef __attribute__((ext_vector_type(8))) _Float16 f16x8;
typedef __attribute__((ext_vector_type(4))) _Float16 f16x4;
typedef __attribute__((ext_vector_type(2))) _Float16 f16x2;
typedef __attribute__((ext_vector_type(4))) float f32x4;
typedef unsigned long long u64;
typedef unsigned int u32;

#define MFMA16(a, b, c) __builtin_amdgcn_mfma_f32_16x16x32_f16(a, b, c, 0, 0, 0)

// ---- Kernel 0: transposed bit-pack, qw-major: bitsT[qw][key] bit j = mask[qw*64+j][key] ----
__global__ __launch_bounds__(256) void mask_tpack_kernel(const int* __restrict__ mask,
                                                         u64* __restrict__ bitsT) {
    int wv = blockIdx.x * 4 + (threadIdx.x >> 6);  // 0..1023
    int lane = threadIdx.x & 63;
    int qw = wv >> 4, kg = wv & 15;
    const int* mp = mask + (size_t)(qw * 64) * SEQ + kg * 256 + lane * 4;
    u64 a0 = 0, a1 = 0, a2 = 0, a3 = 0;
#pragma unroll 16
    for (int j = 0; j < 64; ++j) {
        int4 m = *(const int4*)(mp + (size_t)j * SEQ);
        a0 |= (u64)(m.x != 0) << j;
        a1 |= (u64)(m.y != 0) << j;
        a2 |= (u64)(m.z != 0) << j;
        a3 |= (u64)(m.w != 0) << j;
    }
    u64* dst = bitsT + (size_t)qw * SEQ + kg * 256 + lane * 4;
    ulonglong2 v01 = {a0, a1}, v23 = {a2, a3};
    *(ulonglong2*)(dst) = v01;
    *(ulonglong2*)(dst + 2) = v23;
}

// ---- Kernel 0b: weight prep: Wt[192][512] f16 (n-major, k-contig), bcat[192] f32 ----
// Q weights/bias pre-scaled by 0.125*log2(e): flash computes p = exp2(score).
__global__ __launch_bounds__(256) void wprep_kernel(
    const float* __restrict__ Wq, const float* __restrict__ bq,
    const float* __restrict__ Wk, const float* __restrict__ bk,
    const float* __restrict__ Wv, const float* __restrict__ bv,
    _Float16* __restrict__ Wt, float* __restrict__ bcat) {
    __shared__ float tile[64][65];
    const int bid = blockIdx.x, tid = threadIdx.x;
    const int mat = bid >> 3, k0 = (bid & 7) * 64;
    const float QS = 0.125f * 1.44269504088896f;  // 1/sqrt(64) * log2(e)
    const float* W = (mat == 0) ? Wq : ((mat == 1) ? Wk : Wv);
    const float scale = (mat == 0) ? QS : 1.0f;
    if (bid == 0 && tid < 192) {
        int m2 = tid >> 6, n = tid & 63;
        const float* bb = (m2 == 0) ? bq : ((m2 == 1) ? bk : bv);
        bcat[tid] = bb[n] * ((m2 == 0) ? QS : 1.0f);
    }
    const int n = tid & 63, r0 = tid >> 6;
#pragma unroll
    for (int i = 0; i < 16; ++i) {
        int r = r0 * 16 + i;
        tile[r][n] = W[(size_t)(k0 + r) * 64 + n];
    }
    __syncthreads();
    const int k = tid & 63, n0 = tid >> 6;
#pragma unroll
    for (int i = 0; i < 16; ++i) {
        int nn = n0 * 16 + i;
        Wt[(size_t)(mat * 64 + nn) * IND + k0 + k] = (_Float16)(tile[k][nn] * scale);
    }
}

// ---- Kernel 1: MFMA QKV projection, 3-wave blocks: wave w computes matrix w only ----
// Vt key-interleaved: s' = (s & ~31) + 2*(s&15) + ((s>>4)&1) -- matches flash's packed-P.
__global__ __launch_bounds__(192) void qkv_kernel(const float* __restrict__ X,
    const _Float16* __restrict__ Wt, const float* __restrict__ bcat,
    _Float16* __restrict__ Qh, _Float16* __restrict__ Kh, _Float16* __restrict__ Vt) {
    __shared__ __align__(16) _Float16 xs[16 * 520];  // 16 rows, stride 520 f16 (16.3 KB)
    const int tid = threadIdx.x;
    const int w = tid >> 6, lane = tid & 63, l15 = lane & 15, g = lane >> 4;
    const int m0 = blockIdx.x * 16;

    const float4* src = (const float4*)(X + (size_t)m0 * IND);
#pragma unroll
    for (int u = 0; u < 11; ++u) {
        int idx = u * 192 + tid;
        if (idx < 2048) {
            float4 x = src[idx];
            int row = idx >> 7, c4 = idx & 127;  // 128 float4 per row
            f16x4 h;
            h[0] = (_Float16)x.x; h[1] = (_Float16)x.y;
            h[2] = (_Float16)x.z; h[3] = (_Float16)x.w;
            *(f16x4*)&xs[row * 520 + c4 * 4] = h;
        }
    }
    __syncthreads();

    f32x4 acc[4];
#pragma unroll
    for (int nt = 0; nt < 4; ++nt) acc[nt] = (f32x4){0.f, 0.f, 0.f, 0.f};

    const _Float16* Wm = Wt + (size_t)(w * 64 + l15) * IND + g * 8;
#pragma unroll
    for (int kc = 0; kc < 16; ++kc) {
        f16x8 a = *(const f16x8*)&xs[l15 * 520 + kc * 32 + g * 8];
#pragma unroll
        for (int nt = 0; nt < 4; ++nt)
            acc[nt] = MFMA16(a, *(const f16x8*)(Wm + kc * 32 + (size_t)nt * 16 * IND), acc[nt]);
    }

    const int b = m0 >> 12;
    const int sbase = (m0 & (SEQ - 1)) & ~31;
    const int hi = (m0 >> 4) & 1;
#pragma unroll
    for (int nt = 0; nt < 4; ++nt) {
        float bias = bcat[w * 64 + nt * 16 + l15];
        int ncol = nt * 16 + l15;
        if (w == 0) {
#pragma unroll
            for (int r = 0; r < 4; ++r)
                Qh[(size_t)(m0 + g * 4 + r) * DH + ncol] = (_Float16)(acc[nt][r] + bias);
        } else if (w == 1) {
#pragma unroll
            for (int r = 0; r < 4; ++r)
                Kh[(size_t)(m0 + g * 4 + r) * DH + ncol] = (_Float16)(acc[nt][r] + bias);
        } else {
            _Float16* vb = Vt + ((size_t)b * DH + ncol) * SEQ + sbase + hi;
#pragma unroll
            for (int r = 0; r < 4; ++r)
                vb[2 * (g * 4 + r)] = (_Float16)(acc[nt][r] + bias);
        }
    }
}

// ---- Kernel 2: f16 MFMA flash, 64 q/wave, NSPLIT=8, XCD-pinned (R10 config) ----
// + hand-written 1-tile-ahead register double-buffer: K/V/bits of tile t+1 issued
//   before computing tile t -> L2 gather round-trip off the critical path.
#define LOADT(S, kk)                                                                   \
    do {                                                                               \
        const int _k0 = (kk);                                                          \
        K##S##00 = *(const f16x8*)(Kb + (size_t)(_k0 + l15) * DH + g * 8);             \
        K##S##01 = *(const f16x8*)(Kb + (size_t)(_k0 + l15) * DH + 32 + g * 8);        \
        K##S##10 = *(const f16x8*)(Kb + (size_t)(_k0 + 16 + l15) * DH + g * 8);        \
        K##S##11 = *(const f16x8*)(Kb + (size_t)(_k0 + 16 + l15) * DH + 32 + g * 8);   \
        V##S##0 = *(const f16x8*)(Vb + (size_t)(l15) * SEQ + _k0 + g * 8);             \
        V##S##1 = *(const f16x8*)(Vb + (size_t)(16 + l15) * SEQ + _k0 + g * 8);        \
        V##S##2 = *(const f16x8*)(Vb + (size_t)(32 + l15) * SEQ + _k0 + g * 8);        \
        V##S##3 = *(const f16x8*)(Vb + (size_t)(48 + l15) * SEQ + _k0 + g * 8);        \
        b##S##0 = bitsQ[_k0 + l15];                                                    \
        b##S##1 = bitsQ[_k0 + 16 + l15];                                               \
    } while (0)

#define COMPUTE(S)                                                                     \
    do {                                                                               \
        _Pragma("unroll") for (int mi = 0; mi < 4; ++mi) {                             \
            f32x4 c0 = {0.f, 0.f, 0.f, 0.f}, c1 = {0.f, 0.f, 0.f, 0.f};                \
            c0 = MFMA16(Qa[mi][0], K##S##00, c0);                                      \
            c0 = MFMA16(Qa[mi][1], K##S##01, c0);                                      \
            c1 = MFMA16(Qa[mi][0], K##S##10, c1);                                      \
            c1 = MFMA16(Qa[mi][1], K##S##11, c1);                                      \
            u32 ms0 = (u32)(b##S##0 >> (mi * 16 + (g << 2)));                          \
            u32 ms1 = (u32)(b##S##1 >> (mi * 16 + (g << 2)));                          \
            _Pragma("unroll") for (int r = 0; r < 4; ++r) {                            \
                float s0 = ((ms0 >> r) & 1u) ? c0[r] : 0.0f;                           \
                float s1 = ((ms1 >> r) & 1u) ? c1[r] : 0.0f;                           \
                float p0 = exp2f(s0);                                                  \
                float p1 = exp2f(s1);                                                  \
                lsum[mi * 4 + r] += p0 + p1;                                           \
                f16x2 pp;                                                              \
                pp[0] = (_Float16)p0;                                                  \
                pp[1] = (_Float16)p1;                                                  \
                *(f16x2*)&pbuf[w][mi * 16 + 4 * g + r][2 * l15] = pp;                  \
            }                                                                          \
        }                                                                              \
        _Pragma("unroll") for (int mi = 0; mi < 4; ++mi) {                             \
            f16x8 Pa = *(const f16x8*)&pbuf[w][mi * 16 + l15][g * 8];                  \
            O[mi][0] = MFMA16(Pa, V##S##0, O[mi][0]);                                  \
            O[mi][1] = MFMA16(Pa, V##S##1, O[mi][1]);                                  \
            O[mi][2] = MFMA16(Pa, V##S##2, O[mi][2]);                                  \
            O[mi][3] = MFMA16(Pa, V##S##3, O[mi][3]);                                  \
        }                                                                              \
    } while (0)

__global__ __launch_bounds__(256, 2) void flash_kernel(
    const _Float16* __restrict__ Qh, const _Float16* __restrict__ Kh,
    const _Float16* __restrict__ Vt, const u64* __restrict__ bitsT,
    float* __restrict__ accP, float* __restrict__ lP) {
    constexpr int KPWT = SEQ / NSPLIT;   // 512 keys per split
    constexpr int NT = KPWT / 32;        // 16 tiles (even, power of 2)
    __shared__ __align__(16) _Float16 pbuf[4][64][40];  // [wave][q][keypair], 80B stride

    const int tid = threadIdx.x;
    const int w = tid >> 6, lane = tid & 63, l15 = lane & 15, g = lane >> 4;
    const int bid = blockIdx.x;                      // 512 blocks
    const int xcd = bid & 7, i = bid >> 3;           // i: 0..63
    const int b = xcd >> 1;                          // batch pinned to XCD pair
    const int split = (xcd & 1) * 4 + (i & 3);
    const int qblk = i >> 2;                         // 0..15
    const int q0 = qblk * 256 + w * 64;              // 64 q-rows per wave
    const int k0base = split * KPWT;

    const _Float16* Qb = Qh + (size_t)b * SEQ * DH;
    const _Float16* Kb = Kh + (size_t)b * SEQ * DH;
    const _Float16* Vb = Vt + (size_t)b * DH * SEQ;
    const u64* bitsQ = bitsT + (size_t)(q0 >> 6) * SEQ;

    f16x8 Qa[4][2];
#pragma unroll
    for (int mi = 0; mi < 4; ++mi)
#pragma unroll
        for (int kc = 0; kc < 2; ++kc)
            Qa[mi][kc] = *(const f16x8*)(Qb + (size_t)(q0 + mi * 16 + l15) * DH + kc * 32 + g * 8);

    f32x4 O[4][4];
    float lsum[16];
#pragma unroll
    for (int mi = 0; mi < 4; ++mi)
#pragma unroll
        for (int nd = 0; nd < 4; ++nd) O[mi][nd] = (f32x4){0.f, 0.f, 0.f, 0.f};
#pragma unroll
    for (int j = 0; j < 16; ++j) lsum[j] = 0.f;

    f16x8 KA00, KA01, KA10, KA11, VA0, VA1, VA2, VA3;
    f16x8 KB00, KB01, KB10, KB11, VB0, VB1, VB2, VB3;
    u64 bA0, bA1, bB0, bB1;

    LOADT(A, k0base);  // prologue: tile 0
#pragma unroll 1
    for (int t = 0; t < NT; t += 2) {
        LOADT(B, k0base + (t + 1) * 32);               // prefetch t+1
        COMPUTE(A);                                    // compute t
        LOADT(A, k0base + (((t + 2) & (NT - 1)) * 32));  // prefetch t+2 (wraps harmlessly)
        COMPUTE(B);                                    // compute t+1
    }

#pragma unroll
    for (int j = 0; j < 16; ++j) {
        float v = lsum[j];
        v += __shfl_xor(v, 1);
        v += __shfl_xor(v, 2);
        v += __shfl_xor(v, 4);
        v += __shfl_xor(v, 8);
        lsum[j] = v;
    }
    float* accB = accP + ((size_t)split * BATCH + b) * SEQ * DH;
    float* lB = lP + ((size_t)split * BATCH + b) * SEQ;
    if (l15 == 0) {
#pragma unroll
        for (int mi = 0; mi < 4; ++mi)
#pragma unroll
            for (int r = 0; r < 4; ++r)
                lB[q0 + mi * 16 + 4 * g + r] = lsum[mi * 4 + r];
    }
#pragma unroll
    for (int mi = 0; mi < 4; ++mi)
#pragma unroll
        for (int nd = 0; nd < 4; ++nd)
#pragma unroll
            for (int r = 0; r < 4; ++r)
                accB[(size_t)(q0 + mi * 16 + 4 * g + r) * DH + nd * 16 + l15] = O[mi][nd][r];
}

// ---- Kernel 3: combine key-splits: out = sum(acc)/sum(l) ----
__global__ __launch_bounds__(256) void reduce_kernel(const float* __restrict__ accP,
                                                     const float* __restrict__ lP,
                                                     float* __restrict__ out) {
    int idx = blockIdx.x * 256 + threadIdx.x;
    int bq = idx >> 6, d = idx & 63;
    float a = 0.f, l = 0.f;
#pragma unroll
    for (int s = 0; s < NSPLIT; ++s) {
        a += accP[((size_t)s * BATCH * SEQ + bq) * DH + d];
        l += lP[(size_t)s * BATCH * SEQ + bq];
    }
    out[idx] = a / l;
}

extern "C" void kernel_launch(void* const* d_in, const int* in_sizes, int n_in,
                              void* d_out, int out_size, void* d_ws, size_t ws_size,
                              hipStream_t stream) {
    const float* X = (const float*)d_in[0];
    const int* mask = (const int*)d_in[1];
    const float* Wq = (const float*)d_in[2];
    const float* bq = (const float*)d_in[3];
    const float* Wk = (const float*)d_in[4];
    const float* bk = (const float*)d_in[5];
    const float* Wv = (const float*)d_in[6];
    const float* bv = (const float*)d_in[7];
    float* out = (float*)d_out;

    char* ws = (char*)d_ws;
    _Float16* Qh = (_Float16*)ws;                       // 2 MB
    _Float16* Kh = (_Float16*)(ws + (2u << 20));        // 2 MB
    _Float16* Vt = (_Float16*)(ws + (4u << 20));        // 2 MB (key-interleaved)
    u64* bitsT = (u64*)(ws + (6u << 20));               // 2 MB
    float* accP = (float*)(ws + (8u << 20));            // 32 MB (8 splits, f32)
    float* lP = (float*)(ws + (40u << 20));             // 512 KB
    _Float16* Wt = (_Float16*)(ws + (41u << 20));       // 192 KB
    float* bcat = (float*)(ws + (41u << 20) + (256u << 10));  // 768 B

    wprep_kernel<<<dim3(24), dim3(256), 0, stream>>>(Wq, bq, Wk, bk, Wv, bv, Wt, bcat);
    mask_tpack_kernel<<<dim3(256), dim3(256), 0, stream>>>(mask, bitsT);
    qkv_kernel<<<dim3(BATCH * SEQ / 16), dim3(192), 0, stream>>>(X, Wt, bcat, Qh, Kh, Vt);
    flash_kernel<<<dim3(512), dim3(256), 0, stream>>>(Qh, Kh, Vt, bitsT, accP, lP);
    reduce_kernel<<<dim3(BATCH * SEQ * DH / 256), dim3(256), 0, stream>>>(accP, lP, out);
}

// Round 15
// 100.019 us; speedup vs baseline: 1.9222x; 1.0759x over previous
//
#include <hip/hip_runtime.h>

#define BATCH 4
#define SEQ 4096
#define IND 512
#define DH 64
#define NSPLIT 8

typedef __attribute__((ext_vector_type(8))) _Float16 f16x8;
typedef __attribute__((ext_vector_type(4))) _Float16 f16x4;
typedef __attribute__((ext_vector_type(4))) float f32x4;
typedef unsigned long long u64;
typedef unsigned int u32;

#define MFMA16(a, b, c) __builtin_amdgcn_mfma_f32_16x16x32_f16(a, b, c, 0, 0, 0)

// ---- Kernel 0: bit-pack, key-word-major: bits3[kw][q] bit j = mask[q][kw*64+j] ----
// wave = one kw x 64 q-rows; per iter: 256B coalesced mask read + ballot; one 512B store.
__global__ __launch_bounds__(256) void mask_tpack_kernel(const int* __restrict__ mask,
                                                         u64* __restrict__ bits3) {
    int wv = blockIdx.x * 4 + (threadIdx.x >> 6);  // 0..4095
    int lane = threadIdx.x & 63;
    int kw = wv & 63, q0 = (wv >> 6) * 64;
    u64 keep = 0;
#pragma unroll 8
    for (int i = 0; i < 64; ++i) {
        int val = mask[(size_t)(q0 + i) * SEQ + kw * 64 + lane];
        u64 b = __ballot(val != 0);
        if (lane == i) keep = b;
    }
    bits3[((size_t)kw << 12) + q0 + lane] = keep;  // bit j = key kw*64+j for row q0+lane
}

// ---- Kernel 0b: weight prep: Wt[192][512] f16 (n-major, k-contig), bcat[192] f32 ----
// Q weights/bias pre-scaled by 0.125*log2(e): flash computes p = exp2(score).
__global__ __launch_bounds__(256) void wprep_kernel(
    const float* __restrict__ Wq, const float* __restrict__ bq,
    const float* __restrict__ Wk, const float* __restrict__ bk,
    const float* __restrict__ Wv, const float* __restrict__ bv,
    _Float16* __restrict__ Wt, float* __restrict__ bcat) {
    __shared__ float tile[64][65];
    const int bid = blockIdx.x, tid = threadIdx.x;
    const int mat = bid >> 3, k0 = (bid & 7) * 64;
    const float QS = 0.125f * 1.44269504088896f;  // 1/sqrt(64) * log2(e)
    const float* W = (mat == 0) ? Wq : ((mat == 1) ? Wk : Wv);
    const float scale = (mat == 0) ? QS : 1.0f;
    if (bid == 0 && tid < 192) {
        int m2 = tid >> 6, n = tid & 63;
        const float* bb = (m2 == 0) ? bq : ((m2 == 1) ? bk : bv);
        bcat[tid] = bb[n] * ((m2 == 0) ? QS : 1.0f);
    }
    const int n = tid & 63, r0 = tid >> 6;
#pragma unroll
    for (int i = 0; i < 16; ++i) {
        int r = r0 * 16 + i;
        tile[r][n] = W[(size_t)(k0 + r) * 64 + n];
    }
    __syncthreads();
    const int k = tid & 63, n0 = tid >> 6;
#pragma unroll
    for (int i = 0; i < 16; ++i) {
        int nn = n0 * 16 + i;
        Wt[(size_t)(mat * 64 + nn) * IND + k0 + k] = (_Float16)(tile[k][nn] * scale);
    }
}

// ---- Kernel 1: MFMA QKV projection, 3-wave blocks: wave w computes matrix w only ----
// Vt stored with PV-A-frag key permutation within each 32-block:
//   position p = 8*g + 4*hi + r  holds actual key 16*hi + 4*g + r  (pi(p))
__global__ __launch_bounds__(192) void qkv_kernel(const float* __restrict__ X,
    const _Float16* __restrict__ Wt, const float* __restrict__ bcat,
    _Float16* __restrict__ Qh, _Float16* __restrict__ Kh, _Float16* __restrict__ Vt) {
    __shared__ __align__(16) _Float16 xs[16 * 520];  // 16 rows, stride 520 f16 (16.3 KB)
    const int tid = threadIdx.x;
    const int w = tid >> 6, lane = tid & 63, l15 = lane & 15, g = lane >> 4;
    const int m0 = blockIdx.x * 16;

    const float4* src = (const float4*)(X + (size_t)m0 * IND);
#pragma unroll
    for (int u = 0; u < 11; ++u) {
        int idx = u * 192 + tid;
        if (idx < 2048) {
            float4 x = src[idx];
            int row = idx >> 7, c4 = idx & 127;  // 128 float4 per row
            f16x4 h;
            h[0] = (_Float16)x.x; h[1] = (_Float16)x.y;
            h[2] = (_Float16)x.z; h[3] = (_Float16)x.w;
            *(f16x4*)&xs[row * 520 + c4 * 4] = h;
        }
    }
    __syncthreads();

    f32x4 acc[4];
#pragma unroll
    for (int nt = 0; nt < 4; ++nt) acc[nt] = (f32x4){0.f, 0.f, 0.f, 0.f};

    const _Float16* Wm = Wt + (size_t)(w * 64 + l15) * IND + g * 8;
#pragma unroll
    for (int kc = 0; kc < 16; ++kc) {
        f16x8 a = *(const f16x8*)&xs[l15 * 520 + kc * 32 + g * 8];
#pragma unroll
        for (int nt = 0; nt < 4; ++nt)
            acc[nt] = MFMA16(a, *(const f16x8*)(Wm + kc * 32 + (size_t)nt * 16 * IND), acc[nt]);
    }

    const int b = m0 >> 12;
    const int sbase = (m0 & (SEQ - 1)) & ~31;  // 32-block base
    const int hi = (m0 >> 4) & 1;              // which 16-half of the 32-block
#pragma unroll
    for (int nt = 0; nt < 4; ++nt) {
        float bias = bcat[w * 64 + nt * 16 + l15];
        int ncol = nt * 16 + l15;
        if (w == 0) {
#pragma unroll
            for (int r = 0; r < 4; ++r)
                Qh[(size_t)(m0 + g * 4 + r) * DH + ncol] = (_Float16)(acc[nt][r] + bias);
        } else if (w == 1) {
#pragma unroll
            for (int r = 0; r < 4; ++r)
                Kh[(size_t)(m0 + g * 4 + r) * DH + ncol] = (_Float16)(acc[nt][r] + bias);
        } else {
            // rows m0+4g+r (keys 16*hi+4g+r of the 32-block) -> positions 8g+4hi+r
            f16x4 vv;
#pragma unroll
            for (int r = 0; r < 4; ++r) vv[r] = (_Float16)(acc[nt][r] + bias);
            *(f16x4*)(Vt + ((size_t)b * DH + ncol) * SEQ + sbase + 8 * g + 4 * hi) = vv;
        }
    }
}

// ---- Kernel 2: f16 MFMA flash, swapped QK^T -> in-register P (no LDS at all) ----
// mfma(K,Q) gives C[key][q]: lane holds q=l15, keys 4g+r (c0) / 16+4g+r (c1).
// With Vt's pi permutation these ARE the PV A-frag elements: Pa[e<4]=c0[e], Pa[e>=4]=c1[e-4].
__global__ __launch_bounds__(256, 2) void flash_kernel(
    const _Float16* __restrict__ Qh, const _Float16* __restrict__ Kh,
    const _Float16* __restrict__ Vt, const u64* __restrict__ bits3,
    float* __restrict__ accP, float* __restrict__ lP) {
    constexpr int KPWT = SEQ / NSPLIT;   // 512 keys per split
    constexpr int NT = KPWT / 32;        // 16 tiles

    const int tid = threadIdx.x;
    const int w = tid >> 6, lane = tid & 63, l15 = lane & 15, g = lane >> 4;
    const int bid = blockIdx.x;                      // 512 blocks
    const int xcd = bid & 7, i = bid >> 3;           // batch pinned to XCD pair
    const int b = xcd >> 1;
    const int split = (xcd & 1) * 4 + (i & 3);
    const int qblk = i >> 2;                         // 0..15
    const int q0 = qblk * 256 + w * 64;              // 64 q-rows per wave
    const int k0base = split * KPWT;

    const _Float16* Qb = Qh + (size_t)b * SEQ * DH;
    const _Float16* Kb = Kh + (size_t)b * SEQ * DH;
    const _Float16* Vb = Vt + (size_t)b * DH * SEQ;
    const u64* bitsQ = bits3 + q0;                   // + (kw<<12) + mi*16 + l15

    f16x8 Qa[4][2];
#pragma unroll
    for (int mi = 0; mi < 4; ++mi)
#pragma unroll
        for (int kc = 0; kc < 2; ++kc)
            Qa[mi][kc] = *(const f16x8*)(Qb + (size_t)(q0 + mi * 16 + l15) * DH + kc * 32 + g * 8);

    f32x4 O[4][4];
    float lsum[4];
#pragma unroll
    for (int mi = 0; mi < 4; ++mi)
#pragma unroll
        for (int nd = 0; nd < 4; ++nd) O[mi][nd] = (f32x4){0.f, 0.f, 0.f, 0.f};
#pragma unroll
    for (int j = 0; j < 4; ++j) lsum[j] = 0.f;

    for (int t = 0; t < NT; ++t) {
        const int k0 = k0base + t * 32;
        const int kw = k0 >> 6;
        const int sh0 = (k0 & 32) + 4 * g;           // c0 bit base; c1 adds 16
        f16x8 Kf[2][2], Vf[4];
#pragma unroll
        for (int nt = 0; nt < 2; ++nt)
#pragma unroll
            for (int kc = 0; kc < 2; ++kc)
                Kf[nt][kc] = *(const f16x8*)(Kb + (size_t)(k0 + nt * 16 + l15) * DH + kc * 32 + g * 8);
#pragma unroll
        for (int nd = 0; nd < 4; ++nd)
            Vf[nd] = *(const f16x8*)(Vb + (size_t)(nd * 16 + l15) * SEQ + k0 + g * 8);

#pragma unroll
        for (int mi = 0; mi < 4; ++mi) {
            u64 bw = bitsQ[((size_t)kw << 12) + mi * 16 + l15];  // this q-row's key bits
            u32 ms0 = (u32)(bw >> sh0);
            u32 ms1 = (u32)(bw >> (sh0 + 16));
            f32x4 c0 = {0.f, 0.f, 0.f, 0.f}, c1 = {0.f, 0.f, 0.f, 0.f};
            c0 = MFMA16(Kf[0][0], Qa[mi][0], c0);   // swapped: C[key][q], q = l15
            c0 = MFMA16(Kf[0][1], Qa[mi][1], c0);
            c1 = MFMA16(Kf[1][0], Qa[mi][0], c1);
            c1 = MFMA16(Kf[1][1], Qa[mi][1], c1);
            f16x8 Pa;
            float ls = 0.f;
#pragma unroll
            for (int r = 0; r < 4; ++r) {
                // masked -> score 0 -> p = 2^0 = 1.0 (ref: score 1e-6)
                float s0 = ((ms0 >> r) & 1u) ? c0[r] : 0.0f;
                float s1 = ((ms1 >> r) & 1u) ? c1[r] : 0.0f;
                float p0 = exp2f(s0);
                float p1 = exp2f(s1);
                ls += p0 + p1;
                Pa[r] = (_Float16)p0;      // key position 8g+r   (actual key 4g+r)
                Pa[r + 4] = (_Float16)p1;  // key position 8g+4+r (actual key 16+4g+r)
            }
            lsum[mi] += ls;
            O[mi][0] = MFMA16(Pa, Vf[0], O[mi][0]);
            O[mi][1] = MFMA16(Pa, Vf[1], O[mi][1]);
            O[mi][2] = MFMA16(Pa, Vf[2], O[mi][2]);
            O[mi][3] = MFMA16(Pa, Vf[3], O[mi][3]);
        }
    }

    // row-sum: lane's q = l15 (+mi*16); reduce over g (lane bits 4,5)
#pragma unroll
    for (int j = 0; j < 4; ++j) {
        float v = lsum[j];
        v += __shfl_xor(v, 16);
        v += __shfl_xor(v, 32);
        lsum[j] = v;
    }
    float* accB = accP + ((size_t)split * BATCH + b) * SEQ * DH;
    float* lB = lP + ((size_t)split * BATCH + b) * SEQ;
    if (lane < 16) {
#pragma unroll
        for (int mi = 0; mi < 4; ++mi)
            lB[q0 + mi * 16 + l15] = lsum[mi];
    }
#pragma unroll
    for (int mi = 0; mi < 4; ++mi)
#pragma unroll
        for (int nd = 0; nd < 4; ++nd)
#pragma unroll
            for (int r = 0; r < 4; ++r)
                accB[(size_t)(q0 + mi * 16 + 4 * g + r) * DH + nd * 16 + l15] = O[mi][nd][r];
}

// ---- Kernel 3: combine key-splits: out = sum(acc)/sum(l) ----
__global__ __launch_bounds__(256) void reduce_kernel(const float* __restrict__ accP,
                                                     const float* __restrict__ lP,
                                                     float* __restrict__ out) {
    int idx = blockIdx.x * 256 + threadIdx.x;
    int bq = idx >> 6, d = idx & 63;
    float a = 0.f, l = 0.f;
#pragma unroll
    for (int s = 0; s < NSPLIT; ++s) {
        a += accP[((size_t)s * BATCH * SEQ + bq) * DH + d];
        l += lP[(size_t)s * BATCH * SEQ + bq];
    }
    out[idx] = a / l;
}

extern "C" void kernel_launch(void* const* d_in, const int* in_sizes, int n_in,
                              void* d_out, int out_size, void* d_ws, size_t ws_size,
                              hipStream_t stream) {
    const float* X = (const float*)d_in[0];
    const int* mask = (const int*)d_in[1];
    const float* Wq = (const float*)d_in[2];
    const float* bq = (const float*)d_in[3];
    const float* Wk = (const float*)d_in[4];
    const float* bk = (const float*)d_in[5];
    const float* Wv = (const float*)d_in[6];
    const float* bv = (const float*)d_in[7];
    float* out = (float*)d_out;

    char* ws = (char*)d_ws;
    _Float16* Qh = (_Float16*)ws;                       // 2 MB
    _Float16* Kh = (_Float16*)(ws + (2u << 20));        // 2 MB
    _Float16* Vt = (_Float16*)(ws + (4u << 20));        // 2 MB (pi-permuted keys)
    u64* bits3 = (u64*)(ws + (6u << 20));               // 2 MB [kw][q]
    float* accP = (float*)(ws + (8u << 20));            // 32 MB (8 splits, f32)
    float* lP = (float*)(ws + (40u << 20));             // 512 KB
    _Float16* Wt = (_Float16*)(ws + (41u << 20));       // 192 KB
    float* bcat = (float*)(ws + (41u << 20) + (256u << 10));  // 768 B

    wprep_kernel<<<dim3(24), dim3(256), 0, stream>>>(Wq, bq, Wk, bk, Wv, bv, Wt, bcat);
    mask_tpack_kernel<<<dim3(1024), dim3(256), 0, stream>>>(mask, bits3);
    qkv_kernel<<<dim3(BATCH * SEQ / 16), dim3(192), 0, stream>>>(X, Wt, bcat, Qh, Kh, Vt);
    flash_kernel<<<dim3(512), dim3(256), 0, stream>>>(Qh, Kh, Vt, bits3, accP, lP);
    reduce_kernel<<<dim3(BATCH * SEQ * DH / 256), dim3(256), 0, stream>>>(accP, lP, out);
}